// Round 10
// baseline (246.240 us; speedup 1.0000x reference)
//
#include <hip/hip_runtime.h>
#include <cstddef>
#include <cstdint>

#define SEQ    2048
#define NBATCH 2

typedef unsigned short u16;
typedef unsigned int   u32;
typedef __attribute__((ext_vector_type(8))) short bf16x8;  // 8 bf16 = 4 VGPRs
typedef __attribute__((ext_vector_type(4))) float f32x4;

#if __has_builtin(__builtin_amdgcn_exp2f)
#define EXP2F(x) __builtin_amdgcn_exp2f(x)
#else
#define EXP2F(x) exp2f(x)
#endif

#define GLL16(g, l) __builtin_amdgcn_global_load_lds( \
    (const __attribute__((address_space(1))) void*)(g), \
    (__attribute__((address_space(3))) void*)(l), 16, 0, 0)

__device__ __forceinline__ u32 fbits(float x) { union { float f; u32 u; } c; c.f = x; return c.u; }
__device__ __forceinline__ u16 f2bf(float x) { return (u16)((fbits(x) + 0x8000u) >> 16); }
// pack two floats -> (bf16(hi)<<16) | bf16(lo)
__device__ __forceinline__ u32 pack2bf(float lo, float hi) {
    return __builtin_amdgcn_perm(fbits(hi) + 0x8000u, fbits(lo) + 0x8000u, 0x07060302u);
}

// ---------------------------------------------------------------------------
// weights-only cast: 4 x (1024x1024) fp32 -> bf16.  grid 4096 (1D).
// ---------------------------------------------------------------------------
__global__ __launch_bounds__(256)
void cast_w(const float* __restrict__ wq, const float* __restrict__ wk,
            const float* __restrict__ wv, const float* __restrict__ wo,
            u16* __restrict__ owq, u16* __restrict__ owk,
            u16* __restrict__ owv, u16* __restrict__ owo)
{
    const int w = blockIdx.x >> 10, xi = blockIdx.x & 1023;
    const float* s; u16* d;
    if (w == 0)      { s = wq; d = owq; }
    else if (w == 1) { s = wk; d = owk; }
    else if (w == 2) { s = wv; d = owv; }
    else             { s = wo; d = owo; }
    const int i = xi * 256 + threadIdx.x;
    float4 vv = ((const float4*)s)[i];
    uint2 r; r.x = pack2bf(vv.x, vv.y); r.y = pack2bf(vv.z, vv.w);
    ((uint2*)d)[i] = r;
}

// ---------------------------------------------------------------------------
// QKV GEMM with fused input cast: X fp32 (A, reg-staged + packed to bf16,
// LDS stride 72), W bf16 (B, GLL-staged, stride 64). 128x128 tile, BK=64.
// layout 0: Y bf16 plain [m][1024]
// layout 2: Y bf16 transposed-through-LDS to [n,h,d,l]
// ---------------------------------------------------------------------------
__device__ __forceinline__
void gemm_body_f32A(const float* __restrict__ X, const u16* __restrict__ W,
                    void* __restrict__ Yv, const int layout)
{
    __shared__ u16 smem[128 * 72 + 128 * 64];   // As(72-stride) + Bs(64) = 34.8KB
    u16* As = smem;                              // epilogue T overlays (33.8KB)
    u16* Bs = smem + 128 * 72;

    const int tid  = threadIdx.x;
    const int wave = tid >> 6;
    const int lane = tid & 63;
    const int lm   = lane & 15;
    const int quad = lane >> 4;
    const int m0 = blockIdx.x * 128;
    const int n0 = blockIdx.y * 128;
    const int wr = (wave & 1) * 64;
    const int wc = (wave >> 1) * 64;

    // A staging: row tid>>1 (0..127), 32 floats at (tid&1)*32
    const int srow = tid >> 1;
    const int scol = (tid & 1) * 32;
    const float* xg = X + (size_t)(m0 + srow) * 1024 + scol;
    // B staging (GLL): wave stages rows [w*32, w*32+32)
    const int brow = wave * 32 + (lane >> 3);
    const int bcol = (lane & 7) * 8;
    const u16* wg = W + (size_t)(n0 + brow) * 1024 + bcol;

    float4 pa[8];
    #pragma unroll
    for (int p = 0; p < 8; ++p) pa[p] = ((const float4*)xg)[p];

    f32x4 acc[4][4] = {};

    for (int k0 = 0; k0 < 1024; k0 += 64) {
        __syncthreads();   // previous iter's frag reads done
        #pragma unroll
        for (int p = 0; p < 4; ++p) {
            const float4 a = pa[2 * p], b = pa[2 * p + 1];
            union { u32 w[4]; bf16x8 v; } u;
            u.w[0] = pack2bf(a.x, a.y); u.w[1] = pack2bf(a.z, a.w);
            u.w[2] = pack2bf(b.x, b.y); u.w[3] = pack2bf(b.z, b.w);
            *(bf16x8*)&As[srow * 72 + scol + p * 8] = u.v;
            GLL16(wg + k0 + p * 8 * 1024, &Bs[(wave * 32 + p * 8) * 64]);
        }
        __syncthreads();   // drains vmcnt (GLL) + lgkm -> staging visible
        if (k0 + 64 < 1024) {
            #pragma unroll
            for (int p = 0; p < 8; ++p)
                pa[p] = ((const float4*)(xg + k0 + 64))[p];
        }
        #pragma unroll
        for (int kk = 0; kk < 64; kk += 32) {
            bf16x8 af[4], bf[4];
            #pragma unroll
            for (int t = 0; t < 4; ++t) {
                af[t] = *(const bf16x8*)&As[(wr + t * 16 + lm) * 72 + kk + quad * 8];
                bf[t] = *(const bf16x8*)&Bs[(wc + t * 16 + lm) * 64 + kk + quad * 8];
            }
            #pragma unroll
            for (int i = 0; i < 4; ++i)
                #pragma unroll
                for (int j = 0; j < 4; ++j)
                    acc[i][j] = __builtin_amdgcn_mfma_f32_16x16x32_bf16(af[i], bf[j], acc[i][j], 0, 0, 0);
        }
    }

    if (layout == 0) {
        u16* Y = (u16*)Yv;
        #pragma unroll
        for (int i = 0; i < 4; ++i)
            #pragma unroll
            for (int j = 0; j < 4; ++j) {
                const int C = n0 + wc + j * 16 + lm;
                #pragma unroll
                for (int r = 0; r < 4; ++r) {
                    const int R = m0 + wr + i * 16 + quad * 4 + r;
                    Y[(size_t)R * 1024 + C] = f2bf(acc[i][j][r]);
                }
            }
    } else {
        // transpose 128x128 C-tile through LDS, store [n,h,d,l]
        __syncthreads();            // all frag reads done
        u16* T = smem;              // [d_local][l_local], stride 132
        #pragma unroll
        for (int i = 0; i < 4; ++i)
            #pragma unroll
            for (int j = 0; j < 4; ++j) {
                const int col = wc + j * 16 + lm;
                const int row = wr + i * 16 + quad * 4;
                uint2 v;
                v.x = pack2bf(acc[i][j][0], acc[i][j][1]);
                v.y = pack2bf(acc[i][j][2], acc[i][j][3]);
                *(uint2*)&T[col * 132 + row] = v;
            }
        __syncthreads();
        const int dp = tid >> 1, half = (tid & 1) * 64;
        const int nn = m0 >> 11, l0 = m0 & 2047;
        const int C = n0 + dp, h = C >> 6, d = C & 63;
        u16* Y = (u16*)Yv;
        const size_t base = (((size_t)nn * 16 + h) * 64 + d) * SEQ + l0 + half;
        #pragma unroll
        for (int p = 0; p < 8; ++p) {
            bf16x8 v = *(const bf16x8*)&T[dp * 132 + half + p * 8];
            *(bf16x8*)(Y + base + p * 8) = v;
        }
    }
}

__global__ __launch_bounds__(256, 3)
void gemm_qkv(const float* __restrict__ q, const float* __restrict__ k, const float* __restrict__ v,
              const u16* __restrict__ wq, const u16* __restrict__ wk, const u16* __restrict__ wv,
              u16* __restrict__ qb, u16* __restrict__ kb, u16* __restrict__ vt)
{
    if (blockIdx.z == 0)      gemm_body_f32A(q, wq, qb, 0);
    else if (blockIdx.z == 1) gemm_body_f32A(k, wk, kb, 0);
    else                      gemm_body_f32A(v, wv, vt, 2);
}

// ---------------------------------------------------------------------------
// Output GEMM (R9): 128x64 tiles -> 512 blocks (2/CU), GLL staging.
// ---------------------------------------------------------------------------
__global__ __launch_bounds__(256, 2)
void gemm_out64(const u16* __restrict__ X, const u16* __restrict__ W,
                float* __restrict__ Y, const float* __restrict__ bias)
{
    __shared__ u16 As[128 * 64];
    __shared__ u16 Bs[64 * 64];

    const int tid  = threadIdx.x;
    const int wave = tid >> 6;
    const int lane = tid & 63;
    const int lm   = lane & 15;
    const int quad = lane >> 4;
    const int m0 = blockIdx.x * 128;
    const int n0 = blockIdx.y * 64;
    const int wr = (wave & 1) * 64;
    const int wc = (wave >> 1) * 32;

    const int sr8 = lane >> 3, sc8 = (lane & 7) * 8;
    const u16* xg = X + (size_t)(m0 + wave * 32 + sr8) * 1024 + sc8;
    const u16* wg = W + (size_t)(n0 + wave * 16 + sr8) * 1024 + sc8;

    f32x4 acc[4][2] = {};

    for (int k0 = 0; k0 < 1024; k0 += 64) {
        __syncthreads();
        #pragma unroll
        for (int p = 0; p < 4; ++p)
            GLL16(xg + k0 + p * 8 * 1024, &As[(wave * 32 + p * 8) * 64]);
        #pragma unroll
        for (int p = 0; p < 2; ++p)
            GLL16(wg + k0 + p * 8 * 1024, &Bs[(wave * 16 + p * 8) * 64]);
        __syncthreads();
        #pragma unroll
        for (int kk = 0; kk < 64; kk += 32) {
            bf16x8 af[4], bf[2];
            #pragma unroll
            for (int t = 0; t < 4; ++t)
                af[t] = *(const bf16x8*)&As[(wr + t * 16 + lm) * 64 + kk + quad * 8];
            #pragma unroll
            for (int j = 0; j < 2; ++j)
                bf[j] = *(const bf16x8*)&Bs[(wc + j * 16 + lm) * 64 + kk + quad * 8];
            #pragma unroll
            for (int i = 0; i < 4; ++i)
                #pragma unroll
                for (int j = 0; j < 2; ++j)
                    acc[i][j] = __builtin_amdgcn_mfma_f32_16x16x32_bf16(af[i], bf[j], acc[i][j], 0, 0, 0);
        }
    }

    #pragma unroll
    for (int i = 0; i < 4; ++i)
        #pragma unroll
        for (int j = 0; j < 2; ++j) {
            const int C = n0 + wc + j * 16 + lm;
            const float bv = bias[C];
            #pragma unroll
            for (int r = 0; r < 4; ++r) {
                const int R = m0 + wr + i * 16 + quad * 4 + r;
                Y[(size_t)R * 1024 + C] = acc[i][j][r] + bv;
            }
        }
}

// ---------------------------------------------------------------------------
// Flash attention, S^T hybrid: S^T = K·Q^T (A=K-frag, B=Q-frag) gives each
// lane 4 CONSECUTIVE keys (quad*4+r) per q=lm -> P[q][key] written as packed
// ds_write_b64 (16/wave/chunk vs 64 b16) and read back as K=32 A-frags
// (ds_read_b128). Same 64 MFMAs/chunk as R7; ~half the LDS instructions.
// Max-free softmax; 128-key chunks, two 64-key halves through wave-private
// Ps; reg-prefetch K/V; XCD swizzle. LDS 54.2 KB -> 2 blocks/CU.
// ---------------------------------------------------------------------------
__global__ __launch_bounds__(256, 2)
void flash_attn_bf16(const u16* __restrict__ Qb, const u16* __restrict__ Kb,
                     const u16* __restrict__ VT, const int* __restrict__ mask,
                     u16* __restrict__ O)
{
    __shared__ u16 Ks[128 * 72];      // [key l][d]
    __shared__ u16 Vts[64 * 136];     // [d][key l]
    __shared__ u16 Ps[4][32 * 72];    // per-wave P [q][key-in-half]

    const int tid  = threadIdx.x;
    const int wave = tid >> 6;
    const int lane = tid & 63;
    const int lm   = lane & 15;
    const int quad = lane >> 4;

    // XCD-locality decode: all 16 q-blocks of one (n,h) share wid%8
    const int wid = blockIdx.x;                   // 0..511
    const int idx = wid >> 3;
    const int hn  = (wid & 7) + 8 * (idx & 3);    // 0..31
    const int h   = hn & 15, n = hn >> 4;
    const int wq  = (idx >> 2) * 128 + wave * 32;

    const u16* Qh = Qb + ((size_t)n * SEQ) * 1024 + h * 64;
    const u16* Kh = Kb + ((size_t)n * SEQ) * 1024 + h * 64;
    const u16* Vh = VT + (((size_t)n * 16 + h) * 64) * SEQ;
    const int* mk = mask + (size_t)n * SEQ;
    u16* Pw = &Ps[wave][0];

    // Q fragments resident (B-operand): n=lm -> q, k=quad*8+j -> d
    bf16x8 qf[2][2];
    #pragma unroll
    for (int qt = 0; qt < 2; ++qt)
        #pragma unroll
        for (int s = 0; s < 2; ++s)
            qf[qt][s] = *(const bf16x8*)(Qh + (size_t)(wq + qt * 16 + lm) * 1024 + s * 32 + quad * 8);

    f32x4 o_acc[2][4] = {};   // [qt][dt]: q=quad*4+r, d=lm
    float l_i[2] = {};        // per-lane row sums, q = qt*16+lm

    // staging: K 128 rows x 64 d (2 thr/row); V 64 d x 128 keys (4 thr/row)
    const int kr = tid >> 1, kc = (tid & 1) * 32;
    const int vr = tid >> 2, vc = (tid & 3) * 32;

    bf16x8 ka[4], va[4];
    #pragma unroll
    for (int p = 0; p < 4; ++p) {
        ka[p] = *(const bf16x8*)(Kh + (size_t)kr * 1024 + kc + p * 8);
        va[p] = *(const bf16x8*)(Vh + (size_t)vr * SEQ + vc + p * 8);
    }

    const float cs = 0.125f * 1.44269504f;   // 1/sqrt(64) folded with log2(e)

    for (int c0 = 0; c0 < SEQ; c0 += 128) {
        __syncthreads();   // prior chunk's Ks/Vts reads complete
        #pragma unroll
        for (int p = 0; p < 4; ++p) {
            *(bf16x8*)&Ks[kr * 72 + kc + p * 8]   = ka[p];
            *(bf16x8*)&Vts[vr * 136 + vc + p * 8] = va[p];
        }
        __syncthreads();

        if (c0 + 128 < SEQ) {   // prefetch next chunk under compute
            #pragma unroll
            for (int p = 0; p < 4; ++p) {
                ka[p] = *(const bf16x8*)(Kh + (size_t)(c0 + 128 + kr) * 1024 + kc + p * 8);
                va[p] = *(const bf16x8*)(Vh + (size_t)vr * SEQ + c0 + 128 + vc + p * 8);
            }
        }

        // mask words for this lane's keys: key = c0 + kt*16 + quad*4 + r
        int4 mkv[8];
        #pragma unroll
        for (int kt = 0; kt < 8; ++kt)
            mkv[kt] = *(const int4*)(mk + c0 + kt * 16 + quad * 4);

        // ---- S^T = K·Q^T: D[key=quad*4+r][q=lm]  (32 MFMAs)
        f32x4 st[8][2] = {};
        #pragma unroll
        for (int kt = 0; kt < 8; ++kt) {
            bf16x8 kf0 = *(const bf16x8*)&Ks[(kt * 16 + lm) * 72 + quad * 8];
            bf16x8 kf1 = *(const bf16x8*)&Ks[(kt * 16 + lm) * 72 + 32 + quad * 8];
            #pragma unroll
            for (int qt = 0; qt < 2; ++qt) {
                st[kt][qt] = __builtin_amdgcn_mfma_f32_16x16x32_bf16(kf0, qf[qt][0], st[kt][qt], 0, 0, 0);
                st[kt][qt] = __builtin_amdgcn_mfma_f32_16x16x32_bf16(kf1, qf[qt][1], st[kt][qt], 0, 0, 0);
            }
        }

        // ---- per 64-key half: exp + packed-b64 P store, then K=32 PV
        #pragma unroll
        for (int half = 0; half < 2; ++half) {
            #pragma unroll
            for (int ktl = 0; ktl < 4; ++ktl) {
                const int kt = half * 4 + ktl;
                const int4 mv = mkv[kt];
                const int mm[4] = {mv.x, mv.y, mv.z, mv.w};
                #pragma unroll
                for (int qt = 0; qt < 2; ++qt) {
                    float e[4];
                    #pragma unroll
                    for (int r = 0; r < 4; ++r) {
                        float v = EXP2F(st[kt][qt][r] * cs);
                        v = mm[r] ? v : 0.0f;
                        e[r] = v;
                        l_i[qt] += v;
                    }
                    uint2 w;
                    w.x = pack2bf(e[0], e[1]);
                    w.y = pack2bf(e[2], e[3]);
                    *(uint2*)&Pw[(qt * 16 + lm) * 72 + ktl * 16 + quad * 4] = w;
                }
            }
            #pragma unroll
            for (int ksl = 0; ksl < 2; ++ksl) {
                bf16x8 pf[2];
                #pragma unroll
                for (int qt = 0; qt < 2; ++qt)
                    pf[qt] = *(const bf16x8*)&Pw[(qt * 16 + lm) * 72 + ksl * 32 + quad * 8];
                #pragma unroll
                for (int dt = 0; dt < 4; ++dt) {
                    bf16x8 vf = *(const bf16x8*)&Vts[(dt * 16 + lm) * 136 + half * 64 + ksl * 32 + quad * 8];
                    #pragma unroll
                    for (int qt = 0; qt < 2; ++qt)
                        o_acc[qt][dt] = __builtin_amdgcn_mfma_f32_16x16x32_bf16(pf[qt], vf, o_acc[qt][dt], 0, 0, 0);
                }
            }
        }
    }

    // ---- epilogue: reduce l across quads, redistribute, normalize, store
    float linv[2][4];
    #pragma unroll
    for (int qt = 0; qt < 2; ++qt) {
        float v = l_i[qt];
        v += __shfl_xor(v, 16);
        v += __shfl_xor(v, 32);
        #pragma unroll
        for (int r = 0; r < 4; ++r)
            linv[qt][r] = 1.0f / __shfl(v, quad * 4 + r);
    }
    #pragma unroll
    for (int qt = 0; qt < 2; ++qt)
        #pragma unroll
        for (int dt = 0; dt < 4; ++dt)
            #pragma unroll
            for (int r = 0; r < 4; ++r) {
                const int ql = wq + qt * 16 + quad * 4 + r;
                const int col = h * 64 + dt * 16 + lm;
                O[((size_t)n * SEQ + ql) * 1024 + col] = f2bf(o_acc[qt][dt][r] * linv[qt][r]);
            }
}

// ---------------------------------------------------------------------------
extern "C" void kernel_launch(void* const* d_in, const int* in_sizes, int n_in,
                              void* d_out, int out_size, void* d_ws, size_t ws_size,
                              hipStream_t stream)
{
    const float* values = (const float*)d_in[0];
    const float* keys   = (const float*)d_in[1];
    const float* query  = (const float*)d_in[2];
    const int*   mask   = (const int*)d_in[3];
    const float* W_q    = (const float*)d_in[4];
    const float* W_k    = (const float*)d_in[5];
    const float* W_v    = (const float*)d_in[6];
    const float* W_o    = (const float*)d_in[7];
    const float* b_o    = (const float*)d_in[8];

    const size_t NTOK = (size_t)NBATCH * SEQ * 1024;  // 4194304
    const size_t WSZ  = 1024 * 1024;
    u16* p = (u16*)d_ws;
    u16* qb    = p; p += NTOK;   // q  [n,l,e] bf16
    u16* kb    = p; p += NTOK;   // k  [n,l,e] bf16
    u16* vt    = p; p += NTOK;   // v^T[n,h,d,l] bf16
    u16* attnb = p; p += NTOK;   // attn out [n,l,e] bf16
    u16* wqb   = p; p += WSZ;    // bf16 weight casts
    u16* wkb   = p; p += WSZ;
    u16* wvb   = p; p += WSZ;
    u16* wob   = p; p += WSZ;

    cast_w<<<4096, 256, 0, stream>>>(W_q, W_k, W_v, W_o, wqb, wkb, wvb, wob);

    gemm_qkv<<<dim3(32, 8, 3), 256, 0, stream>>>(query, keys, values,
                                                 wqb, wkb, wvb, qb, kb, vt);

    flash_attn_bf16<<<512, 256, 0, stream>>>(qb, kb, vt, mask, attnb);

    gemm_out64<<<dim3(32, 16), 256, 0, stream>>>(attnb, wob, (float*)d_out, b_o);
}

// Round 11
// 232.778 us; speedup vs baseline: 1.0578x; 1.0578x over previous
//
#include <hip/hip_runtime.h>
#include <cstddef>
#include <cstdint>

#define SEQ    2048
#define NBATCH 2

typedef unsigned short u16;
typedef unsigned int   u32;
typedef __attribute__((ext_vector_type(8))) short bf16x8;  // 8 bf16 = 4 VGPRs
typedef __attribute__((ext_vector_type(4))) float f32x4;

#if __has_builtin(__builtin_amdgcn_exp2f)
#define EXP2F(x) __builtin_amdgcn_exp2f(x)
#else
#define EXP2F(x) exp2f(x)
#endif

#define GLL16(g, l) __builtin_amdgcn_global_load_lds( \
    (const __attribute__((address_space(1))) void*)(g), \
    (__attribute__((address_space(3))) void*)(l), 16, 0, 0)

__device__ __forceinline__ u32 fbits(float x) { union { float f; u32 u; } c; c.f = x; return c.u; }
__device__ __forceinline__ u16 f2bf(float x) { return (u16)((fbits(x) + 0x8000u) >> 16); }
// pack two floats -> (bf16(hi)<<16) | bf16(lo)
__device__ __forceinline__ u32 pack2bf(float lo, float hi) {
    return __builtin_amdgcn_perm(fbits(hi) + 0x8000u, fbits(lo) + 0x8000u, 0x07060302u);
}

// ---------------------------------------------------------------------------
// one cast launch for all 7 tensors. grid (4096, 4)
// ---------------------------------------------------------------------------
__global__ __launch_bounds__(256)
void cast_all(const float* __restrict__ q, const float* __restrict__ k, const float* __restrict__ v,
              const float* __restrict__ wq, const float* __restrict__ wk,
              const float* __restrict__ wv, const float* __restrict__ wo,
              u16* __restrict__ oq, u16* __restrict__ ok, u16* __restrict__ ov,
              u16* __restrict__ owq, u16* __restrict__ owk, u16* __restrict__ owv,
              u16* __restrict__ owo)
{
    const float* s; u16* d; int i;
    if (blockIdx.y == 0)      { s = q; d = oq; i = blockIdx.x * 256 + threadIdx.x; }
    else if (blockIdx.y == 1) { s = k; d = ok; i = blockIdx.x * 256 + threadIdx.x; }
    else if (blockIdx.y == 2) { s = v; d = ov; i = blockIdx.x * 256 + threadIdx.x; }
    else {
        const int w = blockIdx.x >> 10, xi = blockIdx.x & 1023;
        if (w == 0)      { s = wq; d = owq; }
        else if (w == 1) { s = wk; d = owk; }
        else if (w == 2) { s = wv; d = owv; }
        else             { s = wo; d = owo; }
        i = xi * 256 + threadIdx.x;
    }
    float4 vv = ((const float4*)s)[i];
    uint2 r; r.x = pack2bf(vv.x, vv.y); r.y = pack2bf(vv.z, vv.w);
    ((uint2*)d)[i] = r;
}

// ---------------------------------------------------------------------------
// QKV GEMM body (R9-proven): Y = X @ W^T, 128x128 tile, BK=64,
// global_load_lds width-16 staging, unpadded stride-64 LDS.
// layout 0: Y bf16 plain [m][1024]
// layout 2: Y bf16 transposed-through-LDS to [n,h,d,l]
// ---------------------------------------------------------------------------
__device__ __forceinline__
void gemm_body(const u16* __restrict__ X, const u16* __restrict__ W,
               void* __restrict__ Yv, const int layout)
{
    __shared__ u16 smem[16896];   // As(8192) + Bs(8192); epilogue T overlays
    u16* As = smem;
    u16* Bs = smem + 8192;

    const int tid  = threadIdx.x;
    const int wave = tid >> 6;
    const int lane = tid & 63;
    const int lm   = lane & 15;
    const int quad = lane >> 4;
    const int m0 = blockIdx.x * 128;
    const int n0 = blockIdx.y * 128;
    const int wr = (wave & 1) * 64;
    const int wc = (wave >> 1) * 64;

    const int srow = wave * 32 + (lane >> 3);
    const int scol = (lane & 7) * 8;
    const u16* xg = X + (size_t)(m0 + srow) * 1024 + scol;
    const u16* wg = W + (size_t)(n0 + srow) * 1024 + scol;

    f32x4 acc[4][4] = {};

    for (int k0 = 0; k0 < 1024; k0 += 64) {
        __syncthreads();
        #pragma unroll
        for (int p = 0; p < 4; ++p) {
            GLL16(xg + k0 + p * 8 * 1024, &As[(wave * 32 + p * 8) * 64]);
            GLL16(wg + k0 + p * 8 * 1024, &Bs[(wave * 32 + p * 8) * 64]);
        }
        __syncthreads();
        #pragma unroll
        for (int kk = 0; kk < 64; kk += 32) {
            bf16x8 af[4], bf[4];
            #pragma unroll
            for (int t = 0; t < 4; ++t) {
                af[t] = *(const bf16x8*)&As[(wr + t * 16 + lm) * 64 + kk + quad * 8];
                bf[t] = *(const bf16x8*)&Bs[(wc + t * 16 + lm) * 64 + kk + quad * 8];
            }
            #pragma unroll
            for (int i = 0; i < 4; ++i)
                #pragma unroll
                for (int j = 0; j < 4; ++j)
                    acc[i][j] = __builtin_amdgcn_mfma_f32_16x16x32_bf16(af[i], bf[j], acc[i][j], 0, 0, 0);
        }
    }

    if (layout == 0) {
        u16* Y = (u16*)Yv;
        #pragma unroll
        for (int i = 0; i < 4; ++i)
            #pragma unroll
            for (int j = 0; j < 4; ++j) {
                const int C = n0 + wc + j * 16 + lm;
                #pragma unroll
                for (int r = 0; r < 4; ++r) {
                    const int R = m0 + wr + i * 16 + quad * 4 + r;
                    Y[(size_t)R * 1024 + C] = f2bf(acc[i][j][r]);
                }
            }
    } else {
        // transpose 128x128 C-tile through LDS, store [n,h,d,l]
        __syncthreads();
        u16* T = smem;              // [d_local][l_local], stride 132
        #pragma unroll
        for (int i = 0; i < 4; ++i)
            #pragma unroll
            for (int j = 0; j < 4; ++j) {
                const int col = wc + j * 16 + lm;
                const int row = wr + i * 16 + quad * 4;
                uint2 v;
                v.x = pack2bf(acc[i][j][0], acc[i][j][1]);
                v.y = pack2bf(acc[i][j][2], acc[i][j][3]);
                *(uint2*)&T[col * 132 + row] = v;
            }
        __syncthreads();
        const int dp = tid >> 1, half = (tid & 1) * 64;
        const int nn = m0 >> 11, l0 = m0 & 2047;
        const int C = n0 + dp, h = C >> 6, d = C & 63;
        u16* Y = (u16*)Yv;
        const size_t base = (((size_t)nn * 16 + h) * 64 + d) * SEQ + l0 + half;
        #pragma unroll
        for (int p = 0; p < 8; ++p) {
            bf16x8 v = *(const bf16x8*)&T[dp * 132 + half + p * 8];
            *(bf16x8*)(Y + base + p * 8) = v;
        }
    }
}

__global__ __launch_bounds__(256, 3)
void gemm_qkv(const u16* __restrict__ xq, const u16* __restrict__ xk, const u16* __restrict__ xv,
              const u16* __restrict__ wq, const u16* __restrict__ wk, const u16* __restrict__ wv,
              u16* __restrict__ qb, u16* __restrict__ kb, u16* __restrict__ vt)
{
    if (blockIdx.z == 0)      gemm_body(xq, wq, qb, 0);
    else if (blockIdx.z == 1) gemm_body(xk, wk, kb, 0);
    else                      gemm_body(xv, wv, vt, 2);
}

// ---------------------------------------------------------------------------
// Output GEMM: 128x64 tiles, DOUBLE-BUFFERED GLL staging — next K-step's
// loads are in flight during current compute, so the barrier's vmcnt drain
// finds them complete. LDS 48KB -> 2 blocks/CU (grid 512 = 2/CU anyway).
// ---------------------------------------------------------------------------
__global__ __launch_bounds__(256, 2)
void gemm_out64(const u16* __restrict__ X, const u16* __restrict__ W,
                float* __restrict__ Y, const float* __restrict__ bias)
{
    __shared__ u16 As[2][128 * 64];
    __shared__ u16 Bs[2][64 * 64];

    const int tid  = threadIdx.x;
    const int wave = tid >> 6;
    const int lane = tid & 63;
    const int lm   = lane & 15;
    const int quad = lane >> 4;
    const int m0 = blockIdx.x * 128;
    const int n0 = blockIdx.y * 64;
    const int wr = (wave & 1) * 64;
    const int wc = (wave >> 1) * 32;

    const int sr8 = lane >> 3, sc8 = (lane & 7) * 8;
    const u16* xg = X + (size_t)(m0 + wave * 32 + sr8) * 1024 + sc8;
    const u16* wg = W + (size_t)(n0 + wave * 16 + sr8) * 1024 + sc8;

    // preload K-step 0 into buffer 0
    #pragma unroll
    for (int p = 0; p < 4; ++p)
        GLL16(xg + p * 8 * 1024, &As[0][(wave * 32 + p * 8) * 64]);
    #pragma unroll
    for (int p = 0; p < 2; ++p)
        GLL16(wg + p * 8 * 1024, &Bs[0][(wave * 16 + p * 8) * 64]);

    f32x4 acc[4][2] = {};
    __syncthreads();   // buffer 0 ready (vmcnt drained by barrier)

    #pragma unroll
    for (int it = 0; it < 16; ++it) {
        const int cur = it & 1;
        if (it + 1 < 16) {   // issue next-buffer staging; in flight under MFMAs
            const int kn = (it + 1) * 64;
            #pragma unroll
            for (int p = 0; p < 4; ++p)
                GLL16(xg + kn + p * 8 * 1024, &As[cur ^ 1][(wave * 32 + p * 8) * 64]);
            #pragma unroll
            for (int p = 0; p < 2; ++p)
                GLL16(wg + kn + p * 8 * 1024, &Bs[cur ^ 1][(wave * 16 + p * 8) * 64]);
        }
        #pragma unroll
        for (int kk = 0; kk < 64; kk += 32) {
            bf16x8 af[4], bf[2];
            #pragma unroll
            for (int t = 0; t < 4; ++t)
                af[t] = *(const bf16x8*)&As[cur][(wr + t * 16 + lm) * 64 + kk + quad * 8];
            #pragma unroll
            for (int j = 0; j < 2; ++j)
                bf[j] = *(const bf16x8*)&Bs[cur][(wc + j * 16 + lm) * 64 + kk + quad * 8];
            #pragma unroll
            for (int i = 0; i < 4; ++i)
                #pragma unroll
                for (int j = 0; j < 2; ++j)
                    acc[i][j] = __builtin_amdgcn_mfma_f32_16x16x32_bf16(af[i], bf[j], acc[i][j], 0, 0, 0);
        }
        __syncthreads();   // drains vmcnt (next buf ready) + cur reads done
    }

    #pragma unroll
    for (int i = 0; i < 4; ++i)
        #pragma unroll
        for (int j = 0; j < 2; ++j) {
            const int C = n0 + wc + j * 16 + lm;
            const float bv = bias[C];
            #pragma unroll
            for (int r = 0; r < 4; ++r) {
                const int R = m0 + wr + i * 16 + quad * 4 + r;
                Y[(size_t)R * 1024 + C] = acc[i][j][r] + bv;
            }
        }
}

// ---------------------------------------------------------------------------
// Flash attention (R10-proven S^T hybrid): S^T = K·Q^T so each lane holds 4
// consecutive keys -> P written as packed ds_write_b64, read as K=32 A-frags.
// Max-free softmax; 128-key chunks, two 64-key halves through wave-private
// Ps; reg-prefetch K/V; XCD swizzle. LDS 54.2 KB -> 2 blocks/CU.
// ---------------------------------------------------------------------------
__global__ __launch_bounds__(256, 2)
void flash_attn_bf16(const u16* __restrict__ Qb, const u16* __restrict__ Kb,
                     const u16* __restrict__ VT, const int* __restrict__ mask,
                     u16* __restrict__ O)
{
    __shared__ u16 Ks[128 * 72];      // [key l][d]
    __shared__ u16 Vts[64 * 136];     // [d][key l]
    __shared__ u16 Ps[4][32 * 72];    // per-wave P [q][key-in-half]

    const int tid  = threadIdx.x;
    const int wave = tid >> 6;
    const int lane = tid & 63;
    const int lm   = lane & 15;
    const int quad = lane >> 4;

    // XCD-locality decode: all 16 q-blocks of one (n,h) share wid%8
    const int wid = blockIdx.x;                   // 0..511
    const int idx = wid >> 3;
    const int hn  = (wid & 7) + 8 * (idx & 3);    // 0..31
    const int h   = hn & 15, n = hn >> 4;
    const int wq  = (idx >> 2) * 128 + wave * 32;

    const u16* Qh = Qb + ((size_t)n * SEQ) * 1024 + h * 64;
    const u16* Kh = Kb + ((size_t)n * SEQ) * 1024 + h * 64;
    const u16* Vh = VT + (((size_t)n * 16 + h) * 64) * SEQ;
    const int* mk = mask + (size_t)n * SEQ;
    u16* Pw = &Ps[wave][0];

    // Q fragments resident (B-operand): n=lm -> q, k=quad*8+j -> d
    bf16x8 qf[2][2];
    #pragma unroll
    for (int qt = 0; qt < 2; ++qt)
        #pragma unroll
        for (int s = 0; s < 2; ++s)
            qf[qt][s] = *(const bf16x8*)(Qh + (size_t)(wq + qt * 16 + lm) * 1024 + s * 32 + quad * 8);

    f32x4 o_acc[2][4] = {};   // [qt][dt]: q=quad*4+r, d=lm
    float l_i[2] = {};        // per-lane row sums, q = qt*16+lm

    // staging: K 128 rows x 64 d (2 thr/row); V 64 d x 128 keys (4 thr/row)
    const int kr = tid >> 1, kc = (tid & 1) * 32;
    const int vr = tid >> 2, vc = (tid & 3) * 32;

    bf16x8 ka[4], va[4];
    #pragma unroll
    for (int p = 0; p < 4; ++p) {
        ka[p] = *(const bf16x8*)(Kh + (size_t)kr * 1024 + kc + p * 8);
        va[p] = *(const bf16x8*)(Vh + (size_t)vr * SEQ + vc + p * 8);
    }

    const float cs = 0.125f * 1.44269504f;   // 1/sqrt(64) folded with log2(e)

    for (int c0 = 0; c0 < SEQ; c0 += 128) {
        __syncthreads();   // prior chunk's Ks/Vts reads complete
        #pragma unroll
        for (int p = 0; p < 4; ++p) {
            *(bf16x8*)&Ks[kr * 72 + kc + p * 8]   = ka[p];
            *(bf16x8*)&Vts[vr * 136 + vc + p * 8] = va[p];
        }
        __syncthreads();

        if (c0 + 128 < SEQ) {   // prefetch next chunk under compute
            #pragma unroll
            for (int p = 0; p < 4; ++p) {
                ka[p] = *(const bf16x8*)(Kh + (size_t)(c0 + 128 + kr) * 1024 + kc + p * 8);
                va[p] = *(const bf16x8*)(Vh + (size_t)vr * SEQ + c0 + 128 + vc + p * 8);
            }
        }

        // mask words for this lane's keys: key = c0 + kt*16 + quad*4 + r
        int4 mkv[8];
        #pragma unroll
        for (int kt = 0; kt < 8; ++kt)
            mkv[kt] = *(const int4*)(mk + c0 + kt * 16 + quad * 4);

        // ---- S^T = K·Q^T: D[key=quad*4+r][q=lm]  (32 MFMAs)
        f32x4 st[8][2] = {};
        #pragma unroll
        for (int kt = 0; kt < 8; ++kt) {
            bf16x8 kf0 = *(const bf16x8*)&Ks[(kt * 16 + lm) * 72 + quad * 8];
            bf16x8 kf1 = *(const bf16x8*)&Ks[(kt * 16 + lm) * 72 + 32 + quad * 8];
            #pragma unroll
            for (int qt = 0; qt < 2; ++qt) {
                st[kt][qt] = __builtin_amdgcn_mfma_f32_16x16x32_bf16(kf0, qf[qt][0], st[kt][qt], 0, 0, 0);
                st[kt][qt] = __builtin_amdgcn_mfma_f32_16x16x32_bf16(kf1, qf[qt][1], st[kt][qt], 0, 0, 0);
            }
        }

        // ---- per 64-key half: exp + packed-b64 P store, then K=32 PV
        #pragma unroll
        for (int half = 0; half < 2; ++half) {
            #pragma unroll
            for (int ktl = 0; ktl < 4; ++ktl) {
                const int kt = half * 4 + ktl;
                const int4 mv = mkv[kt];
                const int mm[4] = {mv.x, mv.y, mv.z, mv.w};
                #pragma unroll
                for (int qt = 0; qt < 2; ++qt) {
                    float e[4];
                    #pragma unroll
                    for (int r = 0; r < 4; ++r) {
                        float v = EXP2F(st[kt][qt][r] * cs);
                        v = mm[r] ? v : 0.0f;
                        e[r] = v;
                        l_i[qt] += v;
                    }
                    uint2 w;
                    w.x = pack2bf(e[0], e[1]);
                    w.y = pack2bf(e[2], e[3]);
                    *(uint2*)&Pw[(qt * 16 + lm) * 72 + ktl * 16 + quad * 4] = w;
                }
            }
            #pragma unroll
            for (int ksl = 0; ksl < 2; ++ksl) {
                bf16x8 pf[2];
                #pragma unroll
                for (int qt = 0; qt < 2; ++qt)
                    pf[qt] = *(const bf16x8*)&Pw[(qt * 16 + lm) * 72 + ksl * 32 + quad * 8];
                #pragma unroll
                for (int dt = 0; dt < 4; ++dt) {
                    bf16x8 vf = *(const bf16x8*)&Vts[(dt * 16 + lm) * 136 + half * 64 + ksl * 32 + quad * 8];
                    #pragma unroll
                    for (int qt = 0; qt < 2; ++qt)
                        o_acc[qt][dt] = __builtin_amdgcn_mfma_f32_16x16x32_bf16(pf[qt], vf, o_acc[qt][dt], 0, 0, 0);
                }
            }
        }
    }

    // ---- epilogue: reduce l across quads, redistribute, normalize, store
    float linv[2][4];
    #pragma unroll
    for (int qt = 0; qt < 2; ++qt) {
        float v = l_i[qt];
        v += __shfl_xor(v, 16);
        v += __shfl_xor(v, 32);
        #pragma unroll
        for (int r = 0; r < 4; ++r)
            linv[qt][r] = 1.0f / __shfl(v, quad * 4 + r);
    }
    #pragma unroll
    for (int qt = 0; qt < 2; ++qt)
        #pragma unroll
        for (int dt = 0; dt < 4; ++dt)
            #pragma unroll
            for (int r = 0; r < 4; ++r) {
                const int ql = wq + qt * 16 + quad * 4 + r;
                const int col = h * 64 + dt * 16 + lm;
                O[((size_t)n * SEQ + ql) * 1024 + col] = f2bf(o_acc[qt][dt][r] * linv[qt][r]);
            }
}

// ---------------------------------------------------------------------------
extern "C" void kernel_launch(void* const* d_in, const int* in_sizes, int n_in,
                              void* d_out, int out_size, void* d_ws, size_t ws_size,
                              hipStream_t stream)
{
    const float* values = (const float*)d_in[0];
    const float* keys   = (const float*)d_in[1];
    const float* query  = (const float*)d_in[2];
    const int*   mask   = (const int*)d_in[3];
    const float* W_q    = (const float*)d_in[4];
    const float* W_k    = (const float*)d_in[5];
    const float* W_v    = (const float*)d_in[6];
    const float* W_o    = (const float*)d_in[7];
    const float* b_o    = (const float*)d_in[8];

    const size_t NTOK = (size_t)NBATCH * SEQ * 1024;  // 4194304
    const size_t WSZ  = 1024 * 1024;
    u16* p = (u16*)d_ws;
    u16* qb    = p; p += NTOK;   // q  [n,l,e] bf16
    u16* kb    = p; p += NTOK;   // k  [n,l,e] bf16
    u16* vt    = p; p += NTOK;   // v^T[n,h,d,l] bf16
    u16* xq    = p; p += NTOK;   // bf16 input casts
    u16* xk    = p; p += NTOK;
    u16* xv    = p; p += NTOK;
    u16* attnb = p; p += NTOK;   // attn out [n,l,e] bf16
    u16* wqb   = p; p += WSZ;    // bf16 weight casts
    u16* wkb   = p; p += WSZ;
    u16* wvb   = p; p += WSZ;
    u16* wob   = p; p += WSZ;

    cast_all<<<dim3(4096, 4), 256, 0, stream>>>(query, keys, values,
                                                W_q, W_k, W_v, W_o,
                                                xq, xk, xv, wqb, wkb, wvb, wob);

    gemm_qkv<<<dim3(32, 8, 3), 256, 0, stream>>>(xq, xk, xv, wqb, wkb, wvb, qb, kb, vt);

    flash_attn_bf16<<<512, 256, 0, stream>>>(qb, kb, vt, mask, attnb);

    gemm_out64<<<dim3(32, 16), 256, 0, stream>>>(attnb, wob, (float*)d_out, b_o);
}